// Round 8
// baseline (318.604 us; speedup 1.0000x reference)
//
#include <hip/hip_runtime.h>
#include <hip/hip_bf16.h>

#define G     32
#define NPG   512
#define EPG   8192
#define GN    16384        // G*NPG
#define ETOT  (G*EPG)      // 262144
#define CIN   64
#define H     128
#define NB    4
#define S     4096         // T*NPG
#define HEADS 4
#define HD    32
#define QKV   384

typedef __attribute__((ext_vector_type(8))) short short8;
typedef __attribute__((ext_vector_type(4))) short short4v;
typedef __attribute__((ext_vector_type(4))) float floatx4;

// log2(e)/sqrt(32): scores come out in log2 units -> exp2 directly
#define QSCALE 0.2550349419f

// NOTE: no __has_builtin guards — they evaluate false in the HOST pass and broke
// round 7. Direct use compiles in both passes (proven by rounds 3-6's MFMA32).
#define MFMA16(a, b, c) __builtin_amdgcn_mfma_f32_16x16x16bf16_1k(a, b, c, 0, 0, 0)
#define MFMA32(a, b, c) __builtin_amdgcn_mfma_f32_16x16x32_bf16(a, b, c, 0, 0, 0)

__device__ __forceinline__ float bf16_to_f32(unsigned int u) {
    return __uint_as_float(u << 16);
}
__device__ __forceinline__ unsigned short f32_to_bf16(float f) {
    __hip_bfloat16 h = (__hip_bfloat16)f;
    return *(unsigned short*)&h;
}
__device__ __forceinline__ float ldf(const void* p, long i, int f32) {
    return f32 ? ((const float*)p)[i] : bf16_to_f32(((const unsigned short*)p)[i]);
}
__device__ __forceinline__ short4v pack4(float a, float b, float c, float d) {
    unsigned int lo = (unsigned int)f32_to_bf16(a) | ((unsigned int)f32_to_bf16(b) << 16);
    unsigned int hi = (unsigned int)f32_to_bf16(c) | ((unsigned int)f32_to_bf16(d) << 16);
    uint2 u = {lo, hi};
    return *(short4v*)&u;
}

// ---------- runtime dtype detection ----------
__global__ void detect_kernel(const unsigned short* __restrict__ xraw,
                              const int* __restrict__ eiraw, int* __restrict__ flags) {
    __shared__ float smax[256];
    __shared__ int   sor[256];
    int t = threadIdx.x;
    float m = 0.f;
    for (int i = t; i < 4096; i += 256)
        m = fmaxf(m, fabsf(bf16_to_f32(xraw[i])));
    int orv = 0;
    for (int i = t; i < 2048; i += 256)
        orv |= eiraw[2 * i + 1];
    smax[t] = m; sor[t] = orv;
    __syncthreads();
    for (int off = 128; off > 0; off >>= 1) {
        if (t < off) {
            smax[t] = fmaxf(smax[t], smax[t + off]);
            sor[t] |= sor[t + off];
        }
        __syncthreads();
    }
    if (t == 0) {
        flags[0] = (smax[0] > 1000.f) ? 1 : 0;
        flags[1] = (sor[0] == 0) ? 1 : 0;
    }
}

// ---------- fused conversion: everything -> bf16 (weights pre-transposed) ----------
#define XN   (GN*CIN)          // x:      [0,      XN)
#define E1   (XN + H*CIN)      // W1T
#define E2   (E1 + H*H)        // W2T
#define E3   (E2 + QKV*H)      // Wqkv
#define E4   (E3 + H*H)        // Wo
#define E5   (E4 + H)          // b1
#define E6   (E5 + H)          // b2
#define E7   (E6 + QKV)        // bqkv
#define CTOT (E7 + H)          // bo
__global__ void conv_all_kernel(const void* x_raw, const void* W1_raw, const void* b1_raw,
                                const void* W2_raw, const void* b2_raw, const void* Wq_raw,
                                const void* bq_raw, const void* Wo_raw, const void* bo_raw,
                                unsigned short* __restrict__ xb,
                                unsigned short* __restrict__ W1T,
                                unsigned short* __restrict__ W2T,
                                unsigned short* __restrict__ Wqb,
                                unsigned short* __restrict__ Wob,
                                float* __restrict__ b1f, float* __restrict__ b2f,
                                float* __restrict__ bqf, float* __restrict__ bof,
                                const int* __restrict__ flags) {
    int i = blockIdx.x * blockDim.x + threadIdx.x;
    if (i >= CTOT) return;
    int f32 = flags[0];
    if (i < XN) {
        xb[i] = f32_to_bf16(ldf(x_raw, i, f32));
    } else if (i < E1) {       // W1T[c][r] = W1[r][c], [H out][CIN in]
        int j = i - XN, c = j / CIN, r = j - c * CIN;
        W1T[j] = f32_to_bf16(ldf(W1_raw, (long)r * H + c, f32));
    } else if (i < E2) {       // W2T[c][r] = W2[r][c]
        int j = i - E1, c = j >> 7, r = j & 127;
        W2T[j] = f32_to_bf16(ldf(W2_raw, (long)r * H + c, f32));
    } else if (i < E3) {       // in_proj_w already [out][in]
        int j = i - E2;
        Wqb[j] = f32_to_bf16(ldf(Wq_raw, j, f32));
    } else if (i < E4) {
        int j = i - E3;
        Wob[j] = f32_to_bf16(ldf(Wo_raw, j, f32));
    } else if (i < E5) { b1f[i - E4] = ldf(b1_raw, i - E4, f32); }
    else if (i < E6) { b2f[i - E5] = ldf(b2_raw, i - E5, f32); }
    else if (i < E7) { bqf[i - E6] = ldf(bq_raw, i - E6, f32); }
    else             { bof[i - E7] = ldf(bo_raw, i - E7, f32); }
}

// ---------- edges + degree count (fused) ----------
__global__ void edges_kernel(const int* __restrict__ ei, int* __restrict__ srcA,
                             int* __restrict__ dstA, int* __restrict__ cnt,
                             const int* __restrict__ flags) {
    int t = blockIdx.x * blockDim.x + threadIdx.x;
    if (t >= ETOT) return;
    int g = t >> 13, e = t & (EPG - 1);
    int sh = flags[1];
    long long si = ((long long)(g * 2 + 0) * EPG + e) << sh;
    long long di = ((long long)(g * 2 + 1) * EPG + e) << sh;
    int d = g * NPG + ei[di];
    srcA[t] = g * NPG + ei[si];
    dstA[t] = d;
    atomicAdd(&cnt[d], 1);
}

__global__ void scan_kernel(const int* __restrict__ cnt, int* __restrict__ row_start,
                            int* __restrict__ fill_pos, float* __restrict__ dinv) {
    __shared__ int tmp[NPG];
    int g = blockIdx.x, t = threadIdx.x;
    int c = cnt[g * NPG + t];
    tmp[t] = c;
    __syncthreads();
    for (int off = 1; off < NPG; off <<= 1) {
        int v = (t >= off) ? tmp[t - off] : 0;
        __syncthreads();
        tmp[t] += v;
        __syncthreads();
    }
    int excl = tmp[t] - c;
    int rs = g * EPG + excl;
    row_start[g * NPG + t] = rs;
    fill_pos[g * NPG + t]  = rs;
    dinv[g * NPG + t] = 1.0f / sqrtf((float)c + 1.0f);
}

__global__ void fill_kernel(const int* __restrict__ srcA, const int* __restrict__ dstA,
                            int* __restrict__ fill_pos, int* __restrict__ csr_src) {
    int t = blockIdx.x * blockDim.x + threadIdx.x;
    if (t >= ETOT) return;
    int pos = atomicAdd(&fill_pos[dstA[t]], 1);
    csr_src[pos] = srcA[t];
}

// ---------- MFMA GEMM: Y[row][col] = (A[row][:] . B[col][:]) * dinv[row]  (bf16 out)
template<int KD>
__global__ __launch_bounds__(256) void mm_gcn_kernel(const unsigned short* __restrict__ A,
        const unsigned short* __restrict__ B, const float* __restrict__ dinv,
        unsigned short* __restrict__ Y) {
    int tid = threadIdx.x, wave = tid >> 6, lane = tid & 63, m = lane & 15, quad = lane >> 4;
    int row0 = blockIdx.x * 64 + wave * 16;
    floatx4 acc[8] = {};
    for (int kc = 0; kc < KD; kc += 32) {
        short8 af = *(const short8*)&A[(size_t)(row0 + m) * KD + kc + quad * 8];
#pragma unroll
        for (int t = 0; t < 8; t++) {
            short8 bf = *(const short8*)&B[(size_t)(t * 16 + m) * KD + kc + quad * 8];
            acc[t] = MFMA32(af, bf, acc[t]);
        }
    }
    int rbase = row0 + quad * 4;
    float4 dv4 = *(const float4*)&dinv[rbase];
    float dv[4] = {dv4.x, dv4.y, dv4.z, dv4.w};
#pragma unroll
    for (int t = 0; t < 8; t++) {
        int col = t * 16 + m;
#pragma unroll
        for (int r = 0; r < 4; r++)
            Y[(size_t)(rbase + r) * H + col] = f32_to_bf16(acc[t][r] * dv[r]);
    }
}

// ---------- GCN aggregation: 1 wave/node, dword gathers ----------
__global__ __launch_bounds__(256) void agg_kernel(const unsigned short* __restrict__ y,
                           const int* __restrict__ row_start, const int* __restrict__ cnt,
                           const int* __restrict__ csr_src, const float* __restrict__ dinv,
                           const float* __restrict__ bias, unsigned short* __restrict__ hout) {
    int node = blockIdx.x * 4 + (threadIdx.x >> 6);
    int lane = threadIdx.x & 63;
    const unsigned int* y32 = (const unsigned int*)y;   // 64 uints per row
    unsigned int u = y32[(size_t)node * 64 + lane];     // self-loop
    float a0 = bf16_to_f32(u & 0xFFFF), a1 = bf16_to_f32(u >> 16);
    int rs = row_start[node], n = cnt[node];
    int p = 0;
    for (; p + 4 <= n; p += 4) {
        int s0 = csr_src[rs + p + 0];
        int s1 = csr_src[rs + p + 1];
        int s2 = csr_src[rs + p + 2];
        int s3 = csr_src[rs + p + 3];
        unsigned int u0 = y32[(size_t)s0 * 64 + lane];
        unsigned int u1 = y32[(size_t)s1 * 64 + lane];
        unsigned int u2 = y32[(size_t)s2 * 64 + lane];
        unsigned int u3 = y32[(size_t)s3 * 64 + lane];
        a0 += (bf16_to_f32(u0 & 0xFFFF) + bf16_to_f32(u1 & 0xFFFF)) +
              (bf16_to_f32(u2 & 0xFFFF) + bf16_to_f32(u3 & 0xFFFF));
        a1 += (bf16_to_f32(u0 >> 16) + bf16_to_f32(u1 >> 16)) +
              (bf16_to_f32(u2 >> 16) + bf16_to_f32(u3 >> 16));
    }
    for (; p < n; p++) {
        unsigned int uu = y32[(size_t)csr_src[rs + p] * 64 + lane];
        a0 += bf16_to_f32(uu & 0xFFFF);
        a1 += bf16_to_f32(uu >> 16);
    }
    float dv = dinv[node];
    float r0 = a0 * dv + bias[2 * lane];
    float r1 = a1 * dv + bias[2 * lane + 1];
    ((unsigned int*)hout)[(size_t)node * 64 + lane] =
        (unsigned int)f32_to_bf16(r0) | ((unsigned int)f32_to_bf16(r1) << 16);
}

// ---------- QKV GEMM (N=384) with blocked epilogue ----------
__global__ __launch_bounds__(256) void mmqkv_kernel(const unsigned short* __restrict__ A,
        const unsigned short* __restrict__ B, const float* __restrict__ bias,
        unsigned short* __restrict__ Qx, unsigned short* __restrict__ Kx,
        unsigned short* __restrict__ Vtx) {
    int tid = threadIdx.x, wave = tid >> 6, lane = tid & 63, m = lane & 15, quad = lane >> 4;
    int row0 = blockIdx.x * 64 + wave * 16;
    floatx4 acc[24] = {};
    for (int kc = 0; kc < H; kc += 32) {
        short8 af = *(const short8*)&A[(size_t)(row0 + m) * H + kc + quad * 8];
#pragma unroll
        for (int t = 0; t < 24; t++) {
            short8 bf = *(const short8*)&B[(size_t)(t * 16 + m) * H + kc + quad * 8];
            acc[t] = MFMA32(af, bf, acc[t]);
        }
    }
    int rbase = row0 + quad * 4;                    // rows rbase..rbase+3, same batch
    int b = rbase >> 12, s0 = rbase & (S - 1);
#pragma unroll
    for (int t = 0; t < 24; t++) {
        int j = t * 16 + m;                         // 0..383
        float bj = bias[j];
        int jj = j & 127, head = jj >> 5, hd = jj & 31;
        int bh = b * HEADS + head;
        if (t < 8) {                                // Q pre-scaled by log2e/sqrt(32)
#pragma unroll
            for (int r = 0; r < 4; r++)
                Qx[((size_t)bh * S + s0 + r) * HD + hd] =
                    f32_to_bf16((acc[t][r] + bj) * QSCALE);
        } else if (t < 16) {                        // K
#pragma unroll
            for (int r = 0; r < 4; r++)
                Kx[((size_t)bh * S + s0 + r) * HD + hd] = f32_to_bf16(acc[t][r] + bj);
        } else {                                    // V transposed
#pragma unroll
            for (int r = 0; r < 4; r++)
                Vtx[((size_t)bh * HD + hd) * S + s0 + r] = f32_to_bf16(acc[t][r] + bj);
        }
    }
}

// ---------- MFMA flash attention v4: S^T layout, P stays in registers ----------
// QK^T computed as S^T (A=K, B=Q): lane(m,quad) holds p(q=m, key=quad*4+r),
// which IS the 16x16x16 A-frag layout -> PV needs no LDS/shuffle at all.
// l accumulated by ones-MFMA directly in O-row layout. No LDS, no barriers.
// grid (S/128, HEADS, NB), block 256 (4 waves, 32 q/wave).
__global__ __launch_bounds__(256) void attn4_kernel(
        const unsigned short* __restrict__ Qx, const unsigned short* __restrict__ Kx,
        const unsigned short* __restrict__ Vtx, unsigned short* __restrict__ Ob) {
    int tid = threadIdx.x, wave = tid >> 6, lane = tid & 63;
    int m = lane & 15, quad = lane >> 4;
    int bh = blockIdx.z * HEADS + blockIdx.y;
    const unsigned short* Qb  = Qx  + (size_t)bh * S * HD;
    const unsigned short* Kb  = Kx  + (size_t)bh * S * HD;
    const unsigned short* Vtb = Vtx + (size_t)bh * HD * S;

    int q0 = blockIdx.x * 128 + wave * 32;
    short8 qa = *(const short8*)&Qb[(size_t)(q0 + m) * HD + quad * 8];
    short8 qb = *(const short8*)&Qb[(size_t)(q0 + 16 + m) * HD + quad * 8];

    floatx4 oa0 = {}, oa1 = {}, ob0 = {}, ob1 = {};
    floatx4 lca = {}, lcb = {};
    const short4v ones = {(short)0x3F80, (short)0x3F80, (short)0x3F80, (short)0x3F80};

    // prefetch chunk 0
    short8 kf0 = *(const short8*)&Kb[(size_t)m * HD + quad * 8];
    short8 kf1 = *(const short8*)&Kb[(size_t)(m + 16) * HD + quad * 8];
    short4v v00 = *(const short4v*)&Vtb[(size_t)m * S + quad * 4];
    short4v v01 = *(const short4v*)&Vtb[(size_t)m * S + 16 + quad * 4];
    short4v v10 = *(const short4v*)&Vtb[(size_t)(m + 16) * S + quad * 4];
    short4v v11 = *(const short4v*)&Vtb[(size_t)(m + 16) * S + 16 + quad * 4];

    for (int kt = 0; kt < S; kt += 32) {
        floatx4 z = {};
        // S^T: D[key][q]; keys quad*4+r per lane, q = m
        floatx4 sa0 = MFMA32(kf0, qa, z);
        floatx4 sa1 = MFMA32(kf1, qa, z);
        floatx4 sb0 = MFMA32(kf0, qb, z);
        floatx4 sb1 = MFMA32(kf1, qb, z);

        // prefetch next chunk (wrap: harmless valid loads)
        int ktn = (kt + 32) & (S - 1);
        short8 nk0 = *(const short8*)&Kb[(size_t)(ktn + m) * HD + quad * 8];
        short8 nk1 = *(const short8*)&Kb[(size_t)(ktn + m + 16) * HD + quad * 8];
        short4v nv00 = *(const short4v*)&Vtb[(size_t)m * S + ktn + quad * 4];
        short4v nv01 = *(const short4v*)&Vtb[(size_t)m * S + ktn + 16 + quad * 4];
        short4v nv10 = *(const short4v*)&Vtb[(size_t)(m + 16) * S + ktn + quad * 4];
        short4v nv11 = *(const short4v*)&Vtb[(size_t)(m + 16) * S + ktn + 16 + quad * 4];

        // p = exp2(s) (Q pre-scaled by log2e)
        short4v pfa0 = pack4(exp2f(sa0[0]), exp2f(sa0[1]), exp2f(sa0[2]), exp2f(sa0[3]));
        short4v pfa1 = pack4(exp2f(sa1[0]), exp2f(sa1[1]), exp2f(sa1[2]), exp2f(sa1[3]));
        short4v pfb0 = pack4(exp2f(sb0[0]), exp2f(sb0[1]), exp2f(sb0[2]), exp2f(sb0[3]));
        short4v pfb1 = pack4(exp2f(sb1[0]), exp2f(sb1[1]), exp2f(sb1[2]), exp2f(sb1[3]));

        // PV: two K=16 halves per chunk; A-frag = p (already in layout)
        oa0 = MFMA16(pfa0, v00, oa0);  oa0 = MFMA16(pfa1, v01, oa0);
        oa1 = MFMA16(pfa0, v10, oa1);  oa1 = MFMA16(pfa1, v11, oa1);
        ob0 = MFMA16(pfb0, v00, ob0);  ob0 = MFMA16(pfb1, v01, ob0);
        ob1 = MFMA16(pfb0, v10, ob1);  ob1 = MFMA16(pfb1, v11, ob1);
        // l: ones-MFMA sums p over keys, lands in O-row layout
        lca = MFMA16(pfa0, ones, lca); lca = MFMA16(pfa1, ones, lca);
        lcb = MFMA16(pfb0, ones, lcb); lcb = MFMA16(pfb1, ones, lcb);

        kf0 = nk0; kf1 = nk1;
        v00 = nv00; v01 = nv01; v10 = nv10; v11 = nv11;
    }

    float ia[4] = {1.f / lca[0], 1.f / lca[1], 1.f / lca[2], 1.f / lca[3]};
    float ib[4] = {1.f / lcb[0], 1.f / lcb[1], 1.f / lcb[2], 1.f / lcb[3]};

    int growa = blockIdx.z * S + q0 + quad * 4;
    int col = blockIdx.y * HD + m;
#pragma unroll
    for (int r = 0; r < 4; r++) {
        Ob[(size_t)(growa + r) * H + col]           = f32_to_bf16(oa0[r] * ia[r]);
        Ob[(size_t)(growa + r) * H + col + 16]      = f32_to_bf16(oa1[r] * ia[r]);
        Ob[(size_t)(growa + 16 + r) * H + col]      = f32_to_bf16(ob0[r] * ib[r]);
        Ob[(size_t)(growa + 16 + r) * H + col + 16] = f32_to_bf16(ob1[r] * ib[r]);
    }
}

// ---------- output projection GEMM (N=128) + bias, dual-dtype store ----------
__global__ __launch_bounds__(256) void mmout_kernel(const unsigned short* __restrict__ A,
        const unsigned short* __restrict__ B, const float* __restrict__ bias,
        void* __restrict__ out, const int* __restrict__ flags) {
    int tid = threadIdx.x, wave = tid >> 6, lane = tid & 63, m = lane & 15, quad = lane >> 4;
    int row0 = blockIdx.x * 64 + wave * 16;
    floatx4 acc[8] = {};
    for (int kc = 0; kc < H; kc += 32) {
        short8 af = *(const short8*)&A[(size_t)(row0 + m) * H + kc + quad * 8];
#pragma unroll
        for (int t = 0; t < 8; t++) {
            short8 bf = *(const short8*)&B[(size_t)(t * 16 + m) * H + kc + quad * 8];
            acc[t] = MFMA32(af, bf, acc[t]);
        }
    }
    int rbase = row0 + quad * 4;
    int f32o = flags[0];
#pragma unroll
    for (int t = 0; t < 8; t++) {
        int col = t * 16 + m;
        float bj = bias[col];
#pragma unroll
        for (int r = 0; r < 4; r++) {
            float v = acc[t][r] + bj;
            if (f32o) ((float*)out)[(size_t)(rbase + r) * H + col] = v;
            else ((unsigned short*)out)[(size_t)(rbase + r) * H + col] = f32_to_bf16(v);
        }
    }
}

extern "C" void kernel_launch(void* const* d_in, const int* in_sizes, int n_in,
                              void* d_out, int out_size, void* d_ws, size_t ws_size,
                              hipStream_t stream) {
    const void* x_raw    = d_in[0];
    const int*  ei_raw   = (const int*)d_in[1];
    const void* W1_raw   = d_in[2];
    const void* b1_raw   = d_in[3];
    const void* W2_raw   = d_in[4];
    const void* b2_raw   = d_in[5];
    const void* Wq_raw   = d_in[6];
    const void* bq_raw   = d_in[7];
    const void* Wo_raw   = d_in[8];
    const void* bo_raw   = d_in[9];

    char* ws = (char*)d_ws;
    size_t o = 0;
    auto alloc = [&](size_t bytes) { void* p = ws + o; o += (bytes + 1023) & ~1023ull; return p; };

    int*   flags     = (int*)  alloc(1024);
    int*   cnt       = (int*)  alloc((size_t)GN * 4);
    int*   row_start = (int*)  alloc((size_t)GN * 4);
    int*   fill_pos  = (int*)  alloc((size_t)GN * 4);
    float* dinv      = (float*)alloc((size_t)GN * 4);
    int*   srcA      = (int*)  alloc((size_t)ETOT * 4);
    int*   dstA      = (int*)  alloc((size_t)ETOT * 4);
    int*   csr_src   = (int*)  alloc((size_t)ETOT * 4);
    unsigned short* xb   = (unsigned short*)alloc((size_t)GN * CIN * 2);
    unsigned short* W1T  = (unsigned short*)alloc((size_t)H * CIN * 2);
    unsigned short* W2T  = (unsigned short*)alloc((size_t)H * H * 2);
    unsigned short* Wqb  = (unsigned short*)alloc((size_t)QKV * H * 2);
    unsigned short* Wob  = (unsigned short*)alloc((size_t)H * H * 2);
    float* b1f = (float*)alloc(H * 4);
    float* b2f = (float*)alloc(H * 4);
    float* bqf = (float*)alloc(QKV * 4);
    float* bof = (float*)alloc(H * 4);
    unsigned short* y_bf = (unsigned short*)alloc((size_t)GN * H * 2);
    unsigned short* h_bf = (unsigned short*)alloc((size_t)GN * H * 2);
    unsigned short* Qx   = (unsigned short*)alloc((size_t)16 * S * HD * 2);
    unsigned short* Kx   = (unsigned short*)alloc((size_t)16 * S * HD * 2);
    unsigned short* Vtx  = (unsigned short*)alloc((size_t)16 * S * HD * 2);
    unsigned short* Obf  = y_bf;   // y dead after second agg

    (void)hipMemsetAsync(cnt, 0, (size_t)GN * 4, stream);
    detect_kernel<<<1, 256, 0, stream>>>((const unsigned short*)x_raw, ei_raw, flags);

    conv_all_kernel<<<(CTOT + 255) / 256, 256, 0, stream>>>(
        x_raw, W1_raw, b1_raw, W2_raw, b2_raw, Wq_raw, bq_raw, Wo_raw, bo_raw,
        xb, W1T, W2T, Wqb, Wob, b1f, b2f, bqf, bof, flags);

    edges_kernel<<<ETOT / 256, 256, 0, stream>>>(ei_raw, srcA, dstA, cnt, flags);
    scan_kernel<<<G, NPG, 0, stream>>>(cnt, row_start, fill_pos, dinv);
    fill_kernel<<<ETOT / 256, 256, 0, stream>>>(srcA, dstA, fill_pos, csr_src);

    // GCN layer 1
    mm_gcn_kernel<CIN><<<GN / 64, 256, 0, stream>>>(xb, W1T, dinv, y_bf);
    agg_kernel<<<GN / 4, 256, 0, stream>>>(y_bf, row_start, cnt, csr_src, dinv, b1f, h_bf);
    // GCN layer 2
    mm_gcn_kernel<H><<<GN / 64, 256, 0, stream>>>(h_bf, W2T, dinv, y_bf);
    agg_kernel<<<GN / 4, 256, 0, stream>>>(y_bf, row_start, cnt, csr_src, dinv, b2f, h_bf);

    // attention
    mmqkv_kernel<<<GN / 64, 256, 0, stream>>>(h_bf, Wqb, bqf, Qx, Kx, Vtx);
    attn4_kernel<<<dim3(S / 128, HEADS, NB), 256, 0, stream>>>(Qx, Kx, Vtx, Obf);
    mmout_kernel<<<GN / 64, 256, 0, stream>>>(Obf, Wob, bof, d_out, flags);
}

// Round 9
// 316.908 us; speedup vs baseline: 1.0054x; 1.0054x over previous
//
#include <hip/hip_runtime.h>
#include <hip/hip_bf16.h>

#define G     32
#define NPG   512
#define EPG   8192
#define GN    16384        // G*NPG
#define ETOT  (G*EPG)      // 262144
#define CIN   64
#define H     128
#define NB    4
#define S     4096         // T*NPG
#define HEADS 4
#define HD    32
#define QKV   384

typedef __attribute__((ext_vector_type(8))) short short8;
typedef __attribute__((ext_vector_type(4))) short short4v;
typedef __attribute__((ext_vector_type(4))) float floatx4;

// log2(e)/sqrt(32): scores come out in log2 units -> exp2 directly
#define QSCALE 0.2550349419f

// no __has_builtin guards — false in HOST pass (round-7 lesson); direct use OK
#define MFMA16(a, b, c) __builtin_amdgcn_mfma_f32_16x16x16bf16_1k(a, b, c, 0, 0, 0)
#define MFMA32(a, b, c) __builtin_amdgcn_mfma_f32_16x16x32_bf16(a, b, c, 0, 0, 0)

__device__ __forceinline__ float bf16_to_f32(unsigned int u) {
    return __uint_as_float(u << 16);
}
__device__ __forceinline__ unsigned short f32_to_bf16(float f) {
    __hip_bfloat16 h = (__hip_bfloat16)f;
    return *(unsigned short*)&h;
}
// RNE without NaN path (inputs are exp2 results: finite, positive)
__device__ __forceinline__ unsigned int bf16_rne_bits(float f) {
    unsigned int u = __float_as_uint(f);
    return (u + 0x7FFFu + ((u >> 16) & 1u)) >> 16;
}
__device__ __forceinline__ float ldf(const void* p, long i, int f32) {
    return f32 ? ((const float*)p)[i] : bf16_to_f32(((const unsigned short*)p)[i]);
}
__device__ __forceinline__ short4v packexp(floatx4 s) {
    unsigned int lo = bf16_rne_bits(exp2f(s[0])) | (bf16_rne_bits(exp2f(s[1])) << 16);
    unsigned int hi = bf16_rne_bits(exp2f(s[2])) | (bf16_rne_bits(exp2f(s[3])) << 16);
    uint2 u = {lo, hi};
    return *(short4v*)&u;
}

// ---------- runtime dtype detection ----------
__global__ void detect_kernel(const unsigned short* __restrict__ xraw,
                              const int* __restrict__ eiraw, int* __restrict__ flags) {
    __shared__ float smax[256];
    __shared__ int   sor[256];
    int t = threadIdx.x;
    float m = 0.f;
    for (int i = t; i < 4096; i += 256)
        m = fmaxf(m, fabsf(bf16_to_f32(xraw[i])));
    int orv = 0;
    for (int i = t; i < 2048; i += 256)
        orv |= eiraw[2 * i + 1];
    smax[t] = m; sor[t] = orv;
    __syncthreads();
    for (int off = 128; off > 0; off >>= 1) {
        if (t < off) {
            smax[t] = fmaxf(smax[t], smax[t + off]);
            sor[t] |= sor[t + off];
        }
        __syncthreads();
    }
    if (t == 0) {
        flags[0] = (smax[0] > 1000.f) ? 1 : 0;
        flags[1] = (sor[0] == 0) ? 1 : 0;
    }
}

// ---------- fused conversion: everything -> bf16 (weights pre-transposed) ----------
#define XN   (GN*CIN)          // x:      [0,      XN)
#define E1   (XN + H*CIN)      // W1T
#define E2   (E1 + H*H)        // W2T
#define E3   (E2 + QKV*H)      // Wqkv
#define E4   (E3 + H*H)        // Wo
#define E5   (E4 + H)          // b1
#define E6   (E5 + H)          // b2
#define E7   (E6 + QKV)        // bqkv
#define CTOT (E7 + H)          // bo
__global__ void conv_all_kernel(const void* x_raw, const void* W1_raw, const void* b1_raw,
                                const void* W2_raw, const void* b2_raw, const void* Wq_raw,
                                const void* bq_raw, const void* Wo_raw, const void* bo_raw,
                                unsigned short* __restrict__ xb,
                                unsigned short* __restrict__ W1T,
                                unsigned short* __restrict__ W2T,
                                unsigned short* __restrict__ Wqb,
                                unsigned short* __restrict__ Wob,
                                float* __restrict__ b1f, float* __restrict__ b2f,
                                float* __restrict__ bqf, float* __restrict__ bof,
                                const int* __restrict__ flags) {
    int i = blockIdx.x * blockDim.x + threadIdx.x;
    if (i >= CTOT) return;
    int f32 = flags[0];
    if (i < XN) {
        xb[i] = f32_to_bf16(ldf(x_raw, i, f32));
    } else if (i < E1) {       // W1T[c][r] = W1[r][c], [H out][CIN in]
        int j = i - XN, c = j / CIN, r = j - c * CIN;
        W1T[j] = f32_to_bf16(ldf(W1_raw, (long)r * H + c, f32));
    } else if (i < E2) {       // W2T[c][r] = W2[r][c]
        int j = i - E1, c = j >> 7, r = j & 127;
        W2T[j] = f32_to_bf16(ldf(W2_raw, (long)r * H + c, f32));
    } else if (i < E3) {       // in_proj_w already [out][in]
        int j = i - E2;
        Wqb[j] = f32_to_bf16(ldf(Wq_raw, j, f32));
    } else if (i < E4) {
        int j = i - E3;
        Wob[j] = f32_to_bf16(ldf(Wo_raw, j, f32));
    } else if (i < E5) { b1f[i - E4] = ldf(b1_raw, i - E4, f32); }
    else if (i < E6) { b2f[i - E5] = ldf(b2_raw, i - E5, f32); }
    else if (i < E7) { bqf[i - E6] = ldf(bq_raw, i - E6, f32); }
    else             { bof[i - E7] = ldf(bo_raw, i - E7, f32); }
}

// ---------- edges + degree count (fused) ----------
__global__ void edges_kernel(const int* __restrict__ ei, int* __restrict__ srcA,
                             int* __restrict__ dstA, int* __restrict__ cnt,
                             const int* __restrict__ flags) {
    int t = blockIdx.x * blockDim.x + threadIdx.x;
    if (t >= ETOT) return;
    int g = t >> 13, e = t & (EPG - 1);
    int sh = flags[1];
    long long si = ((long long)(g * 2 + 0) * EPG + e) << sh;
    long long di = ((long long)(g * 2 + 1) * EPG + e) << sh;
    int d = g * NPG + ei[di];
    srcA[t] = g * NPG + ei[si];
    dstA[t] = d;
    atomicAdd(&cnt[d], 1);
}

__global__ void scan_kernel(const int* __restrict__ cnt, int* __restrict__ row_start,
                            int* __restrict__ fill_pos, float* __restrict__ dinv) {
    __shared__ int tmp[NPG];
    int g = blockIdx.x, t = threadIdx.x;
    int c = cnt[g * NPG + t];
    tmp[t] = c;
    __syncthreads();
    for (int off = 1; off < NPG; off <<= 1) {
        int v = (t >= off) ? tmp[t - off] : 0;
        __syncthreads();
        tmp[t] += v;
        __syncthreads();
    }
    int excl = tmp[t] - c;
    int rs = g * EPG + excl;
    row_start[g * NPG + t] = rs;
    fill_pos[g * NPG + t]  = rs;
    dinv[g * NPG + t] = 1.0f / sqrtf((float)c + 1.0f);
}

__global__ void fill_kernel(const int* __restrict__ srcA, const int* __restrict__ dstA,
                            int* __restrict__ fill_pos, int* __restrict__ csr_src) {
    int t = blockIdx.x * blockDim.x + threadIdx.x;
    if (t >= ETOT) return;
    int pos = atomicAdd(&fill_pos[dstA[t]], 1);
    csr_src[pos] = srcA[t];
}

// ---------- MFMA GEMM: Y[row][col] = (A[row][:] . B[col][:]) * dinv[row]  (bf16 out)
template<int KD>
__global__ __launch_bounds__(256) void mm_gcn_kernel(const unsigned short* __restrict__ A,
        const unsigned short* __restrict__ B, const float* __restrict__ dinv,
        unsigned short* __restrict__ Y) {
    int tid = threadIdx.x, wave = tid >> 6, lane = tid & 63, m = lane & 15, quad = lane >> 4;
    int row0 = blockIdx.x * 64 + wave * 16;
    floatx4 acc[8] = {};
    for (int kc = 0; kc < KD; kc += 32) {
        short8 af = *(const short8*)&A[(size_t)(row0 + m) * KD + kc + quad * 8];
#pragma unroll
        for (int t = 0; t < 8; t++) {
            short8 bf = *(const short8*)&B[(size_t)(t * 16 + m) * KD + kc + quad * 8];
            acc[t] = MFMA32(af, bf, acc[t]);
        }
    }
    int rbase = row0 + quad * 4;
    float4 dv4 = *(const float4*)&dinv[rbase];
    float dv[4] = {dv4.x, dv4.y, dv4.z, dv4.w};
#pragma unroll
    for (int t = 0; t < 8; t++) {
        int col = t * 16 + m;
#pragma unroll
        for (int r = 0; r < 4; r++)
            Y[(size_t)(rbase + r) * H + col] = f32_to_bf16(acc[t][r] * dv[r]);
    }
}

// ---------- GCN aggregation: 1 wave/node, dword gathers ----------
__global__ __launch_bounds__(256) void agg_kernel(const unsigned short* __restrict__ y,
                           const int* __restrict__ row_start, const int* __restrict__ cnt,
                           const int* __restrict__ csr_src, const float* __restrict__ dinv,
                           const float* __restrict__ bias, unsigned short* __restrict__ hout) {
    int node = blockIdx.x * 4 + (threadIdx.x >> 6);
    int lane = threadIdx.x & 63;
    const unsigned int* y32 = (const unsigned int*)y;   // 64 uints per row
    unsigned int u = y32[(size_t)node * 64 + lane];     // self-loop
    float a0 = bf16_to_f32(u & 0xFFFF), a1 = bf16_to_f32(u >> 16);
    int rs = row_start[node], n = cnt[node];
    int p = 0;
    for (; p + 4 <= n; p += 4) {
        int s0 = csr_src[rs + p + 0];
        int s1 = csr_src[rs + p + 1];
        int s2 = csr_src[rs + p + 2];
        int s3 = csr_src[rs + p + 3];
        unsigned int u0 = y32[(size_t)s0 * 64 + lane];
        unsigned int u1 = y32[(size_t)s1 * 64 + lane];
        unsigned int u2 = y32[(size_t)s2 * 64 + lane];
        unsigned int u3 = y32[(size_t)s3 * 64 + lane];
        a0 += (bf16_to_f32(u0 & 0xFFFF) + bf16_to_f32(u1 & 0xFFFF)) +
              (bf16_to_f32(u2 & 0xFFFF) + bf16_to_f32(u3 & 0xFFFF));
        a1 += (bf16_to_f32(u0 >> 16) + bf16_to_f32(u1 >> 16)) +
              (bf16_to_f32(u2 >> 16) + bf16_to_f32(u3 >> 16));
    }
    for (; p < n; p++) {
        unsigned int uu = y32[(size_t)csr_src[rs + p] * 64 + lane];
        a0 += bf16_to_f32(uu & 0xFFFF);
        a1 += bf16_to_f32(uu >> 16);
    }
    float dv = dinv[node];
    float r0 = a0 * dv + bias[2 * lane];
    float r1 = a1 * dv + bias[2 * lane + 1];
    ((unsigned int*)hout)[(size_t)node * 64 + lane] =
        (unsigned int)f32_to_bf16(r0) | ((unsigned int)f32_to_bf16(r1) << 16);
}

// ---------- QKV GEMM (N=384) with blocked epilogue ----------
__global__ __launch_bounds__(256) void mmqkv_kernel(const unsigned short* __restrict__ A,
        const unsigned short* __restrict__ B, const float* __restrict__ bias,
        unsigned short* __restrict__ Qx, unsigned short* __restrict__ Kx,
        unsigned short* __restrict__ Vtx) {
    int tid = threadIdx.x, wave = tid >> 6, lane = tid & 63, m = lane & 15, quad = lane >> 4;
    int row0 = blockIdx.x * 64 + wave * 16;
    floatx4 acc[24] = {};
    for (int kc = 0; kc < H; kc += 32) {
        short8 af = *(const short8*)&A[(size_t)(row0 + m) * H + kc + quad * 8];
#pragma unroll
        for (int t = 0; t < 24; t++) {
            short8 bf = *(const short8*)&B[(size_t)(t * 16 + m) * H + kc + quad * 8];
            acc[t] = MFMA32(af, bf, acc[t]);
        }
    }
    int rbase = row0 + quad * 4;                    // rows rbase..rbase+3, same batch
    int b = rbase >> 12, s0 = rbase & (S - 1);
#pragma unroll
    for (int t = 0; t < 24; t++) {
        int j = t * 16 + m;                         // 0..383
        float bj = bias[j];
        int jj = j & 127, head = jj >> 5, hd = jj & 31;
        int bh = b * HEADS + head;
        if (t < 8) {                                // Q pre-scaled by log2e/sqrt(32)
#pragma unroll
            for (int r = 0; r < 4; r++)
                Qx[((size_t)bh * S + s0 + r) * HD + hd] =
                    f32_to_bf16((acc[t][r] + bj) * QSCALE);
        } else if (t < 16) {                        // K
#pragma unroll
            for (int r = 0; r < 4; r++)
                Kx[((size_t)bh * S + s0 + r) * HD + hd] = f32_to_bf16(acc[t][r] + bj);
        } else {                                    // V transposed
#pragma unroll
            for (int r = 0; r < 4; r++)
                Vtx[((size_t)bh * HD + hd) * S + s0 + r] = f32_to_bf16(acc[t][r] + bj);
        }
    }
}

// ---------- MFMA flash attention v5: register-P + one-chunk software pipeline ----------
// attn4's S^T layout (P born in MFMA16 A-frag regs, zero LDS) + attn3's lag:
// iteration i issues QK(i) and PV(i-1) as INDEPENDENT MFMA groups; exp(i)
// fills the QK-result latency. grid (S/128, HEADS, NB), block 256.
__global__ __launch_bounds__(256) void attn5_kernel(
        const unsigned short* __restrict__ Qx, const unsigned short* __restrict__ Kx,
        const unsigned short* __restrict__ Vtx, unsigned short* __restrict__ Ob) {
    int tid = threadIdx.x, wave = tid >> 6, lane = tid & 63;
    int m = lane & 15, quad = lane >> 4;
    int bh = blockIdx.z * HEADS + blockIdx.y;
    const unsigned short* Qb  = Qx  + (size_t)bh * S * HD;
    const unsigned short* Kb  = Kx  + (size_t)bh * S * HD;
    const unsigned short* Vtb = Vtx + (size_t)bh * HD * S;

    int q0 = blockIdx.x * 128 + wave * 32;
    short8 qa = *(const short8*)&Qb[(size_t)(q0 + m) * HD + quad * 8];
    short8 qb = *(const short8*)&Qb[(size_t)(q0 + 16 + m) * HD + quad * 8];

    floatx4 oa0 = {}, oa1 = {}, ob0 = {}, ob1 = {};
    floatx4 lca = {}, lcb = {};
    const short4v ones = {(short)0x3F80, (short)0x3F80, (short)0x3F80, (short)0x3F80};
    floatx4 z = {};

    // ---- prologue: chunk 0 ----
    short8 kf0 = *(const short8*)&Kb[(size_t)m * HD + quad * 8];
    short8 kf1 = *(const short8*)&Kb[(size_t)(m + 16) * HD + quad * 8];
    short4v v00 = *(const short4v*)&Vtb[(size_t)m * S + quad * 4];
    short4v v01 = *(const short4v*)&Vtb[(size_t)m * S + 16 + quad * 4];
    short4v v10 = *(const short4v*)&Vtb[(size_t)(m + 16) * S + quad * 4];
    short4v v11 = *(const short4v*)&Vtb[(size_t)(m + 16) * S + 16 + quad * 4];

    floatx4 sa0 = MFMA32(kf0, qa, z);
    floatx4 sa1 = MFMA32(kf1, qa, z);
    floatx4 sb0 = MFMA32(kf0, qb, z);
    floatx4 sb1 = MFMA32(kf1, qb, z);
    short4v pa0 = packexp(sa0), pa1 = packexp(sa1);
    short4v pb0 = packexp(sb0), pb1 = packexp(sb1);
    short4v w00 = v00, w01 = v01, w10 = v10, w11 = v11;

    // load chunk 1
    kf0 = *(const short8*)&Kb[(size_t)(32 + m) * HD + quad * 8];
    kf1 = *(const short8*)&Kb[(size_t)(32 + m + 16) * HD + quad * 8];
    v00 = *(const short4v*)&Vtb[(size_t)m * S + 32 + quad * 4];
    v01 = *(const short4v*)&Vtb[(size_t)m * S + 48 + quad * 4];
    v10 = *(const short4v*)&Vtb[(size_t)(m + 16) * S + 32 + quad * 4];
    v11 = *(const short4v*)&Vtb[(size_t)(m + 16) * S + 48 + quad * 4];

    // invariant at iteration i: kf/v = chunk i, w = V(i-1), pa/pb = P(i-1)
    for (int i = 1; i < S / 32; i++) {
        // QK(i) — independent group 1
        sa0 = MFMA32(kf0, qa, z);
        sa1 = MFMA32(kf1, qa, z);
        sb0 = MFMA32(kf0, qb, z);
        sb1 = MFMA32(kf1, qb, z);

        // PV(i-1) + l(i-1) — independent group 2 (lagged regs)
        oa0 = MFMA16(pa0, w00, oa0);  oa0 = MFMA16(pa1, w01, oa0);
        oa1 = MFMA16(pa0, w10, oa1);  oa1 = MFMA16(pa1, w11, oa1);
        ob0 = MFMA16(pb0, w00, ob0);  ob0 = MFMA16(pb1, w01, ob0);
        ob1 = MFMA16(pb0, w10, ob1);  ob1 = MFMA16(pb1, w11, ob1);
        lca = MFMA16(pa0, ones, lca); lca = MFMA16(pa1, ones, lca);
        lcb = MFMA16(pb0, ones, lcb); lcb = MFMA16(pb1, ones, lcb);

        // rotate V(i) into lag regs
        w00 = v00; w01 = v01; w10 = v10; w11 = v11;

        // load chunk i+1 (wrap on last iter: harmless valid loads)
        int ktn = ((i + 1) * 32) & (S - 1);
        kf0 = *(const short8*)&Kb[(size_t)(ktn + m) * HD + quad * 8];
        kf1 = *(const short8*)&Kb[(size_t)(ktn + m + 16) * HD + quad * 8];
        v00 = *(const short4v*)&Vtb[(size_t)m * S + ktn + quad * 4];
        v01 = *(const short4v*)&Vtb[(size_t)m * S + ktn + 16 + quad * 4];
        v10 = *(const short4v*)&Vtb[(size_t)(m + 16) * S + ktn + quad * 4];
        v11 = *(const short4v*)&Vtb[(size_t)(m + 16) * S + ktn + 16 + quad * 4];

        // exp(i) — fills QK(i) result latency
        pa0 = packexp(sa0); pa1 = packexp(sa1);
        pb0 = packexp(sb0); pb1 = packexp(sb1);
    }

    // epilogue: PV(last)
    oa0 = MFMA16(pa0, w00, oa0);  oa0 = MFMA16(pa1, w01, oa0);
    oa1 = MFMA16(pa0, w10, oa1);  oa1 = MFMA16(pa1, w11, oa1);
    ob0 = MFMA16(pb0, w00, ob0);  ob0 = MFMA16(pb1, w01, ob0);
    ob1 = MFMA16(pb0, w10, ob1);  ob1 = MFMA16(pb1, w11, ob1);
    lca = MFMA16(pa0, ones, lca); lca = MFMA16(pa1, ones, lca);
    lcb = MFMA16(pb0, ones, lcb); lcb = MFMA16(pb1, ones, lcb);

    float ia[4] = {1.f / lca[0], 1.f / lca[1], 1.f / lca[2], 1.f / lca[3]};
    float ib[4] = {1.f / lcb[0], 1.f / lcb[1], 1.f / lcb[2], 1.f / lcb[3]};

    int growa = blockIdx.z * S + q0 + quad * 4;
    int col = blockIdx.y * HD + m;
#pragma unroll
    for (int r = 0; r < 4; r++) {
        Ob[(size_t)(growa + r) * H + col]           = f32_to_bf16(oa0[r] * ia[r]);
        Ob[(size_t)(growa + r) * H + col + 16]      = f32_to_bf16(oa1[r] * ia[r]);
        Ob[(size_t)(growa + 16 + r) * H + col]      = f32_to_bf16(ob0[r] * ib[r]);
        Ob[(size_t)(growa + 16 + r) * H + col + 16] = f32_to_bf16(ob1[r] * ib[r]);
    }
}

// ---------- output projection GEMM (N=128) + bias, dual-dtype store ----------
__global__ __launch_bounds__(256) void mmout_kernel(const unsigned short* __restrict__ A,
        const unsigned short* __restrict__ B, const float* __restrict__ bias,
        void* __restrict__ out, const int* __restrict__ flags) {
    int tid = threadIdx.x, wave = tid >> 6, lane = tid & 63, m = lane & 15, quad = lane >> 4;
    int row0 = blockIdx.x * 64 + wave * 16;
    floatx4 acc[8] = {};
    for (int kc = 0; kc < H; kc += 32) {
        short8 af = *(const short8*)&A[(size_t)(row0 + m) * H + kc + quad * 8];
#pragma unroll
        for (int t = 0; t < 8; t++) {
            short8 bf = *(const short8*)&B[(size_t)(t * 16 + m) * H + kc + quad * 8];
            acc[t] = MFMA32(af, bf, acc[t]);
        }
    }
    int rbase = row0 + quad * 4;
    int f32o = flags[0];
#pragma unroll
    for (int t = 0; t < 8; t++) {
        int col = t * 16 + m;
        float bj = bias[col];
#pragma unroll
        for (int r = 0; r < 4; r++) {
            float v = acc[t][r] + bj;
            if (f32o) ((float*)out)[(size_t)(rbase + r) * H + col] = v;
            else ((unsigned short*)out)[(size_t)(rbase + r) * H + col] = f32_to_bf16(v);
        }
    }
}

extern "C" void kernel_launch(void* const* d_in, const int* in_sizes, int n_in,
                              void* d_out, int out_size, void* d_ws, size_t ws_size,
                              hipStream_t stream) {
    const void* x_raw    = d_in[0];
    const int*  ei_raw   = (const int*)d_in[1];
    const void* W1_raw   = d_in[2];
    const void* b1_raw   = d_in[3];
    const void* W2_raw   = d_in[4];
    const void* b2_raw   = d_in[5];
    const void* Wq_raw   = d_in[6];
    const void* bq_raw   = d_in[7];
    const void* Wo_raw   = d_in[8];
    const void* bo_raw   = d_in[9];

    char* ws = (char*)d_ws;
    size_t o = 0;
    auto alloc = [&](size_t bytes) { void* p = ws + o; o += (bytes + 1023) & ~1023ull; return p; };

    int*   flags     = (int*)  alloc(1024);
    int*   cnt       = (int*)  alloc((size_t)GN * 4);
    int*   row_start = (int*)  alloc((size_t)GN * 4);
    int*   fill_pos  = (int*)  alloc((size_t)GN * 4);
    float* dinv      = (float*)alloc((size_t)GN * 4);
    int*   srcA      = (int*)  alloc((size_t)ETOT * 4);
    int*   dstA      = (int*)  alloc((size_t)ETOT * 4);
    int*   csr_src   = (int*)  alloc((size_t)ETOT * 4);
    unsigned short* xb   = (unsigned short*)alloc((size_t)GN * CIN * 2);
    unsigned short* W1T  = (unsigned short*)alloc((size_t)H * CIN * 2);
    unsigned short* W2T  = (unsigned short*)alloc((size_t)H * H * 2);
    unsigned short* Wqb  = (unsigned short*)alloc((size_t)QKV * H * 2);
    unsigned short* Wob  = (unsigned short*)alloc((size_t)H * H * 2);
    float* b1f = (float*)alloc(H * 4);
    float* b2f = (float*)alloc(H * 4);
    float* bqf = (float*)alloc(QKV * 4);
    float* bof = (float*)alloc(H * 4);
    unsigned short* y_bf = (unsigned short*)alloc((size_t)GN * H * 2);
    unsigned short* h_bf = (unsigned short*)alloc((size_t)GN * H * 2);
    unsigned short* Qx   = (unsigned short*)alloc((size_t)16 * S * HD * 2);
    unsigned short* Kx   = (unsigned short*)alloc((size_t)16 * S * HD * 2);
    unsigned short* Vtx  = (unsigned short*)alloc((size_t)16 * S * HD * 2);
    unsigned short* Obf  = y_bf;   // y dead after second agg

    (void)hipMemsetAsync(cnt, 0, (size_t)GN * 4, stream);
    detect_kernel<<<1, 256, 0, stream>>>((const unsigned short*)x_raw, ei_raw, flags);

    conv_all_kernel<<<(CTOT + 255) / 256, 256, 0, stream>>>(
        x_raw, W1_raw, b1_raw, W2_raw, b2_raw, Wq_raw, bq_raw, Wo_raw, bo_raw,
        xb, W1T, W2T, Wqb, Wob, b1f, b2f, bqf, bof, flags);

    edges_kernel<<<ETOT / 256, 256, 0, stream>>>(ei_raw, srcA, dstA, cnt, flags);
    scan_kernel<<<G, NPG, 0, stream>>>(cnt, row_start, fill_pos, dinv);
    fill_kernel<<<ETOT / 256, 256, 0, stream>>>(srcA, dstA, fill_pos, csr_src);

    // GCN layer 1
    mm_gcn_kernel<CIN><<<GN / 64, 256, 0, stream>>>(xb, W1T, dinv, y_bf);
    agg_kernel<<<GN / 4, 256, 0, stream>>>(y_bf, row_start, cnt, csr_src, dinv, b1f, h_bf);
    // GCN layer 2
    mm_gcn_kernel<H><<<GN / 64, 256, 0, stream>>>(h_bf, W2T, dinv, y_bf);
    agg_kernel<<<GN / 4, 256, 0, stream>>>(y_bf, row_start, cnt, csr_src, dinv, b2f, h_bf);

    // attention
    mmqkv_kernel<<<GN / 64, 256, 0, stream>>>(h_bf, Wqb, bqf, Qx, Kx, Vtx);
    attn5_kernel<<<dim3(S / 128, HEADS, NB), 256, 0, stream>>>(Qx, Kx, Vtx, Obf);
    mmout_kernel<<<GN / 64, 256, 0, stream>>>(Obf, Wob, bof, d_out, flags);
}

// Round 10
// 316.273 us; speedup vs baseline: 1.0074x; 1.0020x over previous
//
#include <hip/hip_runtime.h>
#include <hip/hip_bf16.h>

#define G     32
#define NPG   512
#define EPG   8192
#define GN    16384        // G*NPG
#define ETOT  (G*EPG)      // 262144
#define CIN   64
#define H     128
#define NB    4
#define S     4096         // T*NPG
#define HEADS 4
#define HD    32
#define QKV   384

typedef __attribute__((ext_vector_type(8))) short short8;
typedef __attribute__((ext_vector_type(4))) short short4v;
typedef __attribute__((ext_vector_type(4))) float floatx4;

// 1/sqrt(32): natural-log units, __expf does the log2e fold internally (1 mul)
#define QSCALE 0.17677669529663687f

// no __has_builtin guards — false in HOST pass (round-7 lesson); direct use OK
#define MFMA16(a, b, c) __builtin_amdgcn_mfma_f32_16x16x16bf16_1k(a, b, c, 0, 0, 0)
#define MFMA32(a, b, c) __builtin_amdgcn_mfma_f32_16x16x32_bf16(a, b, c, 0, 0, 0)

__device__ __forceinline__ float bf16_to_f32(unsigned int u) {
    return __uint_as_float(u << 16);
}
__device__ __forceinline__ unsigned short f32_to_bf16(float f) {
    __hip_bfloat16 h = (__hip_bfloat16)f;
    return *(unsigned short*)&h;
}
__device__ __forceinline__ float ldf(const void* p, long i, int f32) {
    return f32 ? ((const float*)p)[i] : bf16_to_f32(((const unsigned short*)p)[i]);
}
// exp + truncate-to-bf16 pack: 4x(v_mul+v_exp) + 2x v_perm. Truncation (vs RNE)
// is self-consistent: the SAME p feeds PV and the l ones-MFMA, so the o/l ratio
// cancels the bias. perm sel 0x07060302: D = [b.b2,b.b3,a.b2,a.b3] = hi halves.
__device__ __forceinline__ short4v packp(floatx4 s) {
    float e0 = __expf(s[0]), e1 = __expf(s[1]);
    float e2 = __expf(s[2]), e3 = __expf(s[3]);
    unsigned int lo = __builtin_amdgcn_perm(__float_as_uint(e1), __float_as_uint(e0),
                                            0x07060302u);
    unsigned int hi = __builtin_amdgcn_perm(__float_as_uint(e3), __float_as_uint(e2),
                                            0x07060302u);
    uint2 u = {lo, hi};
    return *(short4v*)&u;
}

// ---------- runtime dtype detection ----------
__global__ void detect_kernel(const unsigned short* __restrict__ xraw,
                              const int* __restrict__ eiraw, int* __restrict__ flags) {
    __shared__ float smax[256];
    __shared__ int   sor[256];
    int t = threadIdx.x;
    float m = 0.f;
    for (int i = t; i < 4096; i += 256)
        m = fmaxf(m, fabsf(bf16_to_f32(xraw[i])));
    int orv = 0;
    for (int i = t; i < 2048; i += 256)
        orv |= eiraw[2 * i + 1];
    smax[t] = m; sor[t] = orv;
    __syncthreads();
    for (int off = 128; off > 0; off >>= 1) {
        if (t < off) {
            smax[t] = fmaxf(smax[t], smax[t + off]);
            sor[t] |= sor[t + off];
        }
        __syncthreads();
    }
    if (t == 0) {
        flags[0] = (smax[0] > 1000.f) ? 1 : 0;
        flags[1] = (sor[0] == 0) ? 1 : 0;
    }
}

// ---------- fused conversion: everything -> bf16 (weights pre-transposed) ----------
#define XN   (GN*CIN)          // x:      [0,      XN)
#define E1   (XN + H*CIN)      // W1T
#define E2   (E1 + H*H)        // W2T
#define E3   (E2 + QKV*H)      // Wqkv
#define E4   (E3 + H*H)        // Wo
#define E5   (E4 + H)          // b1
#define E6   (E5 + H)          // b2
#define E7   (E6 + QKV)        // bqkv
#define CTOT (E7 + H)          // bo
__global__ void conv_all_kernel(const void* x_raw, const void* W1_raw, const void* b1_raw,
                                const void* W2_raw, const void* b2_raw, const void* Wq_raw,
                                const void* bq_raw, const void* Wo_raw, const void* bo_raw,
                                unsigned short* __restrict__ xb,
                                unsigned short* __restrict__ W1T,
                                unsigned short* __restrict__ W2T,
                                unsigned short* __restrict__ Wqb,
                                unsigned short* __restrict__ Wob,
                                float* __restrict__ b1f, float* __restrict__ b2f,
                                float* __restrict__ bqf, float* __restrict__ bof,
                                const int* __restrict__ flags) {
    int i = blockIdx.x * blockDim.x + threadIdx.x;
    if (i >= CTOT) return;
    int f32 = flags[0];
    if (i < XN) {
        xb[i] = f32_to_bf16(ldf(x_raw, i, f32));
    } else if (i < E1) {       // W1T[c][r] = W1[r][c], [H out][CIN in]
        int j = i - XN, c = j / CIN, r = j - c * CIN;
        W1T[j] = f32_to_bf16(ldf(W1_raw, (long)r * H + c, f32));
    } else if (i < E2) {       // W2T[c][r] = W2[r][c]
        int j = i - E1, c = j >> 7, r = j & 127;
        W2T[j] = f32_to_bf16(ldf(W2_raw, (long)r * H + c, f32));
    } else if (i < E3) {       // in_proj_w already [out][in]
        int j = i - E2;
        Wqb[j] = f32_to_bf16(ldf(Wq_raw, j, f32));
    } else if (i < E4) {
        int j = i - E3;
        Wob[j] = f32_to_bf16(ldf(Wo_raw, j, f32));
    } else if (i < E5) { b1f[i - E4] = ldf(b1_raw, i - E4, f32); }
    else if (i < E6) { b2f[i - E5] = ldf(b2_raw, i - E5, f32); }
    else if (i < E7) { bqf[i - E6] = ldf(bq_raw, i - E6, f32); }
    else             { bof[i - E7] = ldf(bo_raw, i - E7, f32); }
}

// ---------- edges + degree count (fused) ----------
__global__ void edges_kernel(const int* __restrict__ ei, int* __restrict__ srcA,
                             int* __restrict__ dstA, int* __restrict__ cnt,
                             const int* __restrict__ flags) {
    int t = blockIdx.x * blockDim.x + threadIdx.x;
    if (t >= ETOT) return;
    int g = t >> 13, e = t & (EPG - 1);
    int sh = flags[1];
    long long si = ((long long)(g * 2 + 0) * EPG + e) << sh;
    long long di = ((long long)(g * 2 + 1) * EPG + e) << sh;
    int d = g * NPG + ei[di];
    srcA[t] = g * NPG + ei[si];
    dstA[t] = d;
    atomicAdd(&cnt[d], 1);
}

__global__ void scan_kernel(const int* __restrict__ cnt, int* __restrict__ row_start,
                            int* __restrict__ fill_pos, float* __restrict__ dinv) {
    __shared__ int tmp[NPG];
    int g = blockIdx.x, t = threadIdx.x;
    int c = cnt[g * NPG + t];
    tmp[t] = c;
    __syncthreads();
    for (int off = 1; off < NPG; off <<= 1) {
        int v = (t >= off) ? tmp[t - off] : 0;
        __syncthreads();
        tmp[t] += v;
        __syncthreads();
    }
    int excl = tmp[t] - c;
    int rs = g * EPG + excl;
    row_start[g * NPG + t] = rs;
    fill_pos[g * NPG + t]  = rs;
    dinv[g * NPG + t] = 1.0f / sqrtf((float)c + 1.0f);
}

__global__ void fill_kernel(const int* __restrict__ srcA, const int* __restrict__ dstA,
                            int* __restrict__ fill_pos, int* __restrict__ csr_src) {
    int t = blockIdx.x * blockDim.x + threadIdx.x;
    if (t >= ETOT) return;
    int pos = atomicAdd(&fill_pos[dstA[t]], 1);
    csr_src[pos] = srcA[t];
}

// ---------- MFMA GEMM: Y[row][col] = (A[row][:] . B[col][:]) * dinv[row]  (bf16 out)
template<int KD>
__global__ __launch_bounds__(256) void mm_gcn_kernel(const unsigned short* __restrict__ A,
        const unsigned short* __restrict__ B, const float* __restrict__ dinv,
        unsigned short* __restrict__ Y) {
    int tid = threadIdx.x, wave = tid >> 6, lane = tid & 63, m = lane & 15, quad = lane >> 4;
    int row0 = blockIdx.x * 64 + wave * 16;
    floatx4 acc[8] = {};
    for (int kc = 0; kc < KD; kc += 32) {
        short8 af = *(const short8*)&A[(size_t)(row0 + m) * KD + kc + quad * 8];
#pragma unroll
        for (int t = 0; t < 8; t++) {
            short8 bf = *(const short8*)&B[(size_t)(t * 16 + m) * KD + kc + quad * 8];
            acc[t] = MFMA32(af, bf, acc[t]);
        }
    }
    int rbase = row0 + quad * 4;
    float4 dv4 = *(const float4*)&dinv[rbase];
    float dv[4] = {dv4.x, dv4.y, dv4.z, dv4.w};
#pragma unroll
    for (int t = 0; t < 8; t++) {
        int col = t * 16 + m;
#pragma unroll
        for (int r = 0; r < 4; r++)
            Y[(size_t)(rbase + r) * H + col] = f32_to_bf16(acc[t][r] * dv[r]);
    }
}

// ---------- GCN aggregation: 1 wave/node, dword gathers ----------
__global__ __launch_bounds__(256) void agg_kernel(const unsigned short* __restrict__ y,
                           const int* __restrict__ row_start, const int* __restrict__ cnt,
                           const int* __restrict__ csr_src, const float* __restrict__ dinv,
                           const float* __restrict__ bias, unsigned short* __restrict__ hout) {
    int node = blockIdx.x * 4 + (threadIdx.x >> 6);
    int lane = threadIdx.x & 63;
    const unsigned int* y32 = (const unsigned int*)y;   // 64 uints per row
    unsigned int u = y32[(size_t)node * 64 + lane];     // self-loop
    float a0 = bf16_to_f32(u & 0xFFFF), a1 = bf16_to_f32(u >> 16);
    int rs = row_start[node], n = cnt[node];
    int p = 0;
    for (; p + 4 <= n; p += 4) {
        int s0 = csr_src[rs + p + 0];
        int s1 = csr_src[rs + p + 1];
        int s2 = csr_src[rs + p + 2];
        int s3 = csr_src[rs + p + 3];
        unsigned int u0 = y32[(size_t)s0 * 64 + lane];
        unsigned int u1 = y32[(size_t)s1 * 64 + lane];
        unsigned int u2 = y32[(size_t)s2 * 64 + lane];
        unsigned int u3 = y32[(size_t)s3 * 64 + lane];
        a0 += (bf16_to_f32(u0 & 0xFFFF) + bf16_to_f32(u1 & 0xFFFF)) +
              (bf16_to_f32(u2 & 0xFFFF) + bf16_to_f32(u3 & 0xFFFF));
        a1 += (bf16_to_f32(u0 >> 16) + bf16_to_f32(u1 >> 16)) +
              (bf16_to_f32(u2 >> 16) + bf16_to_f32(u3 >> 16));
    }
    for (; p < n; p++) {
        unsigned int uu = y32[(size_t)csr_src[rs + p] * 64 + lane];
        a0 += bf16_to_f32(uu & 0xFFFF);
        a1 += bf16_to_f32(uu >> 16);
    }
    float dv = dinv[node];
    float r0 = a0 * dv + bias[2 * lane];
    float r1 = a1 * dv + bias[2 * lane + 1];
    ((unsigned int*)hout)[(size_t)node * 64 + lane] =
        (unsigned int)f32_to_bf16(r0) | ((unsigned int)f32_to_bf16(r1) << 16);
}

// ---------- QKV GEMM (N=384) with blocked epilogue ----------
__global__ __launch_bounds__(256) void mmqkv_kernel(const unsigned short* __restrict__ A,
        const unsigned short* __restrict__ B, const float* __restrict__ bias,
        unsigned short* __restrict__ Qx, unsigned short* __restrict__ Kx,
        unsigned short* __restrict__ Vtx) {
    int tid = threadIdx.x, wave = tid >> 6, lane = tid & 63, m = lane & 15, quad = lane >> 4;
    int row0 = blockIdx.x * 64 + wave * 16;
    floatx4 acc[24] = {};
    for (int kc = 0; kc < H; kc += 32) {
        short8 af = *(const short8*)&A[(size_t)(row0 + m) * H + kc + quad * 8];
#pragma unroll
        for (int t = 0; t < 24; t++) {
            short8 bf = *(const short8*)&B[(size_t)(t * 16 + m) * H + kc + quad * 8];
            acc[t] = MFMA32(af, bf, acc[t]);
        }
    }
    int rbase = row0 + quad * 4;                    // rows rbase..rbase+3, same batch
    int b = rbase >> 12, s0 = rbase & (S - 1);
#pragma unroll
    for (int t = 0; t < 24; t++) {
        int j = t * 16 + m;                         // 0..383
        float bj = bias[j];
        int jj = j & 127, head = jj >> 5, hd = jj & 31;
        int bh = b * HEADS + head;
        if (t < 8) {                                // Q pre-scaled by 1/sqrt(32)
#pragma unroll
            for (int r = 0; r < 4; r++)
                Qx[((size_t)bh * S + s0 + r) * HD + hd] =
                    f32_to_bf16((acc[t][r] + bj) * QSCALE);
        } else if (t < 16) {                        // K
#pragma unroll
            for (int r = 0; r < 4; r++)
                Kx[((size_t)bh * S + s0 + r) * HD + hd] = f32_to_bf16(acc[t][r] + bj);
        } else {                                    // V transposed
#pragma unroll
            for (int r = 0; r < 4; r++)
                Vtx[((size_t)bh * HD + hd) * S + s0 + r] = f32_to_bf16(acc[t][r] + bj);
        }
    }
}

// ---------- MFMA flash attention v6: v5 pipeline + minimal-VALU softmax ----------
// S^T layout (P born in MFMA16 A-frag regs, zero LDS) + one-chunk lag pipeline.
// exp via __expf (mul+v_exp), pack via v_perm truncation (1 instr / 2 elems).
// grid (S/128, HEADS, NB), block 256.
__global__ __launch_bounds__(256) void attn6_kernel(
        const unsigned short* __restrict__ Qx, const unsigned short* __restrict__ Kx,
        const unsigned short* __restrict__ Vtx, unsigned short* __restrict__ Ob) {
    int tid = threadIdx.x, wave = tid >> 6, lane = tid & 63;
    int m = lane & 15, quad = lane >> 4;
    int bh = blockIdx.z * HEADS + blockIdx.y;
    const unsigned short* Qb  = Qx  + (size_t)bh * S * HD;
    const unsigned short* Kb  = Kx  + (size_t)bh * S * HD;
    const unsigned short* Vtb = Vtx + (size_t)bh * HD * S;

    int q0 = blockIdx.x * 128 + wave * 32;
    short8 qa = *(const short8*)&Qb[(size_t)(q0 + m) * HD + quad * 8];
    short8 qb = *(const short8*)&Qb[(size_t)(q0 + 16 + m) * HD + quad * 8];

    floatx4 oa0 = {}, oa1 = {}, ob0 = {}, ob1 = {};
    floatx4 lca = {}, lcb = {};
    const short4v ones = {(short)0x3F80, (short)0x3F80, (short)0x3F80, (short)0x3F80};
    floatx4 z = {};

    // ---- prologue: chunk 0 ----
    short8 kf0 = *(const short8*)&Kb[(size_t)m * HD + quad * 8];
    short8 kf1 = *(const short8*)&Kb[(size_t)(m + 16) * HD + quad * 8];
    short4v v00 = *(const short4v*)&Vtb[(size_t)m * S + quad * 4];
    short4v v01 = *(const short4v*)&Vtb[(size_t)m * S + 16 + quad * 4];
    short4v v10 = *(const short4v*)&Vtb[(size_t)(m + 16) * S + quad * 4];
    short4v v11 = *(const short4v*)&Vtb[(size_t)(m + 16) * S + 16 + quad * 4];

    floatx4 sa0 = MFMA32(kf0, qa, z);
    floatx4 sa1 = MFMA32(kf1, qa, z);
    floatx4 sb0 = MFMA32(kf0, qb, z);
    floatx4 sb1 = MFMA32(kf1, qb, z);
    short4v pa0 = packp(sa0), pa1 = packp(sa1);
    short4v pb0 = packp(sb0), pb1 = packp(sb1);
    short4v w00 = v00, w01 = v01, w10 = v10, w11 = v11;

    // load chunk 1
    kf0 = *(const short8*)&Kb[(size_t)(32 + m) * HD + quad * 8];
    kf1 = *(const short8*)&Kb[(size_t)(32 + m + 16) * HD + quad * 8];
    v00 = *(const short4v*)&Vtb[(size_t)m * S + 32 + quad * 4];
    v01 = *(const short4v*)&Vtb[(size_t)m * S + 48 + quad * 4];
    v10 = *(const short4v*)&Vtb[(size_t)(m + 16) * S + 32 + quad * 4];
    v11 = *(const short4v*)&Vtb[(size_t)(m + 16) * S + 48 + quad * 4];

    // invariant at iteration i: kf/v = chunk i, w = V(i-1), pa/pb = P(i-1)
    for (int i = 1; i < S / 32; i++) {
        // QK(i) — independent group 1
        sa0 = MFMA32(kf0, qa, z);
        sa1 = MFMA32(kf1, qa, z);
        sb0 = MFMA32(kf0, qb, z);
        sb1 = MFMA32(kf1, qb, z);

        // PV(i-1) + l(i-1) — independent group 2 (lagged regs)
        oa0 = MFMA16(pa0, w00, oa0);  oa0 = MFMA16(pa1, w01, oa0);
        oa1 = MFMA16(pa0, w10, oa1);  oa1 = MFMA16(pa1, w11, oa1);
        ob0 = MFMA16(pb0, w00, ob0);  ob0 = MFMA16(pb1, w01, ob0);
        ob1 = MFMA16(pb0, w10, ob1);  ob1 = MFMA16(pb1, w11, ob1);
        lca = MFMA16(pa0, ones, lca); lca = MFMA16(pa1, ones, lca);
        lcb = MFMA16(pb0, ones, lcb); lcb = MFMA16(pb1, ones, lcb);

        // rotate V(i) into lag regs
        w00 = v00; w01 = v01; w10 = v10; w11 = v11;

        // load chunk i+1 (wrap on last iter: harmless valid loads)
        int ktn = ((i + 1) * 32) & (S - 1);
        kf0 = *(const short8*)&Kb[(size_t)(ktn + m) * HD + quad * 8];
        kf1 = *(const short8*)&Kb[(size_t)(ktn + m + 16) * HD + quad * 8];
        v00 = *(const short4v*)&Vtb[(size_t)m * S + ktn + quad * 4];
        v01 = *(const short4v*)&Vtb[(size_t)m * S + ktn + 16 + quad * 4];
        v10 = *(const short4v*)&Vtb[(size_t)(m + 16) * S + ktn + quad * 4];
        v11 = *(const short4v*)&Vtb[(size_t)(m + 16) * S + ktn + 16 + quad * 4];

        // exp(i) — fills QK(i) result latency
        pa0 = packp(sa0); pa1 = packp(sa1);
        pb0 = packp(sb0); pb1 = packp(sb1);
    }

    // epilogue: PV(last)
    oa0 = MFMA16(pa0, w00, oa0);  oa0 = MFMA16(pa1, w01, oa0);
    oa1 = MFMA16(pa0, w10, oa1);  oa1 = MFMA16(pa1, w11, oa1);
    ob0 = MFMA16(pb0, w00, ob0);  ob0 = MFMA16(pb1, w01, ob0);
    ob1 = MFMA16(pb0, w10, ob1);  ob1 = MFMA16(pb1, w11, ob1);
    lca = MFMA16(pa0, ones, lca); lca = MFMA16(pa1, ones, lca);
    lcb = MFMA16(pb0, ones, lcb); lcb = MFMA16(pb1, ones, lcb);

    float ia[4] = {1.f / lca[0], 1.f / lca[1], 1.f / lca[2], 1.f / lca[3]};
    float ib[4] = {1.f / lcb[0], 1.f / lcb[1], 1.f / lcb[2], 1.f / lcb[3]};

    int growa = blockIdx.z * S + q0 + quad * 4;
    int col = blockIdx.y * HD + m;
#pragma unroll
    for (int r = 0; r < 4; r++) {
        Ob[(size_t)(growa + r) * H + col]           = f32_to_bf16(oa0[r] * ia[r]);
        Ob[(size_t)(growa + r) * H + col + 16]      = f32_to_bf16(oa1[r] * ia[r]);
        Ob[(size_t)(growa + 16 + r) * H + col]      = f32_to_bf16(ob0[r] * ib[r]);
        Ob[(size_t)(growa + 16 + r) * H + col + 16] = f32_to_bf16(ob1[r] * ib[r]);
    }
}

// ---------- output projection GEMM (N=128) + bias, dual-dtype store ----------
__global__ __launch_bounds__(256) void mmout_kernel(const unsigned short* __restrict__ A,
        const unsigned short* __restrict__ B, const float* __restrict__ bias,
        void* __restrict__ out, const int* __restrict__ flags) {
    int tid = threadIdx.x, wave = tid >> 6, lane = tid & 63, m = lane & 15, quad = lane >> 4;
    int row0 = blockIdx.x * 64 + wave * 16;
    floatx4 acc[8] = {};
    for (int kc = 0; kc < H; kc += 32) {
        short8 af = *(const short8*)&A[(size_t)(row0 + m) * H + kc + quad * 8];
#pragma unroll
        for (int t = 0; t < 8; t++) {
            short8 bf = *(const short8*)&B[(size_t)(t * 16 + m) * H + kc + quad * 8];
            acc[t] = MFMA32(af, bf, acc[t]);
        }
    }
    int rbase = row0 + quad * 4;
    int f32o = flags[0];
#pragma unroll
    for (int t = 0; t < 8; t++) {
        int col = t * 16 + m;
        float bj = bias[col];
#pragma unroll
        for (int r = 0; r < 4; r++) {
            float v = acc[t][r] + bj;
            if (f32o) ((float*)out)[(size_t)(rbase + r) * H + col] = v;
            else ((unsigned short*)out)[(size_t)(rbase + r) * H + col] = f32_to_bf16(v);
        }
    }
}

extern "C" void kernel_launch(void* const* d_in, const int* in_sizes, int n_in,
                              void* d_out, int out_size, void* d_ws, size_t ws_size,
                              hipStream_t stream) {
    const void* x_raw    = d_in[0];
    const int*  ei_raw   = (const int*)d_in[1];
    const void* W1_raw   = d_in[2];
    const void* b1_raw   = d_in[3];
    const void* W2_raw   = d_in[4];
    const void* b2_raw   = d_in[5];
    const void* Wq_raw   = d_in[6];
    const void* bq_raw   = d_in[7];
    const void* Wo_raw   = d_in[8];
    const void* bo_raw   = d_in[9];

    char* ws = (char*)d_ws;
    size_t o = 0;
    auto alloc = [&](size_t bytes) { void* p = ws + o; o += (bytes + 1023) & ~1023ull; return p; };

    int*   flags     = (int*)  alloc(1024);
    int*   cnt       = (int*)  alloc((size_t)GN * 4);
    int*   row_start = (int*)  alloc((size_t)GN * 4);
    int*   fill_pos  = (int*)  alloc((size_t)GN * 4);
    float* dinv      = (float*)alloc((size_t)GN * 4);
    int*   srcA      = (int*)  alloc((size_t)ETOT * 4);
    int*   dstA      = (int*)  alloc((size_t)ETOT * 4);
    int*   csr_src   = (int*)  alloc((size_t)ETOT * 4);
    unsigned short* xb   = (unsigned short*)alloc((size_t)GN * CIN * 2);
    unsigned short* W1T  = (unsigned short*)alloc((size_t)H * CIN * 2);
    unsigned short* W2T  = (unsigned short*)alloc((size_t)H * H * 2);
    unsigned short* Wqb  = (unsigned short*)alloc((size_t)QKV * H * 2);
    unsigned short* Wob  = (unsigned short*)alloc((size_t)H * H * 2);
    float* b1f = (float*)alloc(H * 4);
    float* b2f = (float*)alloc(H * 4);
    float* bqf = (float*)alloc(QKV * 4);
    float* bof = (float*)alloc(H * 4);
    unsigned short* y_bf = (unsigned short*)alloc((size_t)GN * H * 2);
    unsigned short* h_bf = (unsigned short*)alloc((size_t)GN * H * 2);
    unsigned short* Qx   = (unsigned short*)alloc((size_t)16 * S * HD * 2);
    unsigned short* Kx   = (unsigned short*)alloc((size_t)16 * S * HD * 2);
    unsigned short* Vtx  = (unsigned short*)alloc((size_t)16 * S * HD * 2);
    unsigned short* Obf  = y_bf;   // y dead after second agg

    (void)hipMemsetAsync(cnt, 0, (size_t)GN * 4, stream);
    detect_kernel<<<1, 256, 0, stream>>>((const unsigned short*)x_raw, ei_raw, flags);

    conv_all_kernel<<<(CTOT + 255) / 256, 256, 0, stream>>>(
        x_raw, W1_raw, b1_raw, W2_raw, b2_raw, Wq_raw, bq_raw, Wo_raw, bo_raw,
        xb, W1T, W2T, Wqb, Wob, b1f, b2f, bqf, bof, flags);

    edges_kernel<<<ETOT / 256, 256, 0, stream>>>(ei_raw, srcA, dstA, cnt, flags);
    scan_kernel<<<G, NPG, 0, stream>>>(cnt, row_start, fill_pos, dinv);
    fill_kernel<<<ETOT / 256, 256, 0, stream>>>(srcA, dstA, fill_pos, csr_src);

    // GCN layer 1
    mm_gcn_kernel<CIN><<<GN / 64, 256, 0, stream>>>(xb, W1T, dinv, y_bf);
    agg_kernel<<<GN / 4, 256, 0, stream>>>(y_bf, row_start, cnt, csr_src, dinv, b1f, h_bf);
    // GCN layer 2
    mm_gcn_kernel<H><<<GN / 64, 256, 0, stream>>>(h_bf, W2T, dinv, y_bf);
    agg_kernel<<<GN / 4, 256, 0, stream>>>(y_bf, row_start, cnt, csr_src, dinv, b2f, h_bf);

    // attention
    mmqkv_kernel<<<GN / 64, 256, 0, stream>>>(h_bf, Wqb, bqf, Qx, Kx, Vtx);
    attn6_kernel<<<dim3(S / 128, HEADS, NB), 256, 0, stream>>>(Qx, Kx, Vtx, Obf);
    mmout_kernel<<<GN / 64, 256, 0, stream>>>(Obf, Wob, bof, d_out, flags);
}